// Round 1
// baseline (252.363 us; speedup 1.0000x reference)
//
#include <hip/hip_runtime.h>
#include <hip/hip_bf16.h>

#define B_   2
#define CIN  384
#define NPIX 3136
#define NH   8
#define KD   16
#define DHEAD 64
#define NHKD 128
#define QKW  256
#define DHD  512
#define EPSW 1e-5f

typedef __attribute__((ext_vector_type(8))) short vshort8;
typedef __attribute__((ext_vector_type(4))) short vshort4;
typedef __attribute__((ext_vector_type(4))) float vfloat4;
typedef __attribute__((ext_vector_type(16))) float vfloat16;
typedef __attribute__((ext_vector_type(4))) unsigned int vuint4;
typedef __attribute__((ext_vector_type(2))) int vint2;

static __device__ __forceinline__ float bf2f(short s) {
    unsigned int u = ((unsigned int)(unsigned short)s) << 16;
    return __builtin_bit_cast(float, u);
}
static __device__ __forceinline__ short f2bf(float f) {
    unsigned int u = __builtin_bit_cast(unsigned int, f);
    unsigned int lsb = (u >> 16) & 1u;
    u += 0x7fffu + lsb;
    return (short)(u >> 16);
}
static __device__ __forceinline__ float pget(const void* p, int i, int f32) {
    return f32 ? ((const float*)p)[i] : bf2f(((const short*)p)[i]);
}
static __device__ __forceinline__ unsigned int cvtpk(float lo, float hi) {
    unsigned int r;
    asm("v_cvt_pk_bf16_f32 %0, %1, %2" : "=v"(r) : "v"(lo), "v"(hi));
    return r;
}

// ---- inline dtype detect: fp32 low-halves carry wild exponent fields -------
static __device__ __forceinline__ int detect_f32(const unsigned short* x) {
    int lane = threadIdx.x & 63;
    bool big = false;
#pragma unroll
    for (int j = 0; j < 8; j++) {
        int e = (x[(lane * 8 + j) * 2] >> 7) & 0xFF;
        big = big || (e >= 0xC0);
    }
    unsigned long long bal = __ballot(big);
    return __popcll(bal) >= 32;
}

// ======= prep: convert weights + BN tables + transpose x, one dispatch ======
__global__ __launch_bounds__(256) void prep_kernel(
    const void* __restrict__ x,
    const void* __restrict__ wq, const void* __restrict__ wk,
    const void* __restrict__ wv, const void* __restrict__ wp,
    short* __restrict__ wB, short* __restrict__ xT,
    const void* qg, const void* qb, const void* qm, const void* qv,
    const void* kg, const void* kb, const void* km, const void* kv,
    const void* vg, const void* vb, const void* vm, const void* vv,
    const void* pg, const void* pb, const void* pm, const void* pv,
    float* __restrict__ scA, float* __restrict__ shA)
{
    __shared__ short tile[32][33];
    int f32 = detect_f32((const unsigned short*)x);
    int id = blockIdx.x;
    int t = threadIdx.x;

    if (id < 1920) {
        int i = id * 256 + t;
        const void* src; int j;
        if (i < 49152)       { src = wq; j = i; }
        else if (i < 98304)  { src = wk; j = i - 49152; }
        else if (i < 294912) { src = wv; j = i - 98304; }
        else                 { src = wp; j = i - 294912; }
        wB[i] = f32 ? f2bf(((const float*)src)[j]) : ((const short*)src)[j];
        if (i < 1152) {
            const void *g, *bb, *mn, *vr;
            if (i < 128)      { g = qg; bb = qb; mn = qm; vr = qv; j = i; }
            else if (i < 256) { g = kg; bb = kb; mn = km; vr = kv; j = i - 128; }
            else if (i < 768) { g = vg; bb = vb; mn = vm; vr = vv; j = i - 256; }
            else              { g = pg; bb = pb; mn = pm; vr = pv; j = i - 768; }
            float iv = rsqrtf(pget(vr, j, f32) + EPSW);
            float s = pget(g, j, f32) * iv;
            scA[i] = s;
            shA[i] = pget(bb, j, f32) - pget(mn, j, f32) * s;
        }
        return;
    }

    int tid2 = id - 1920;                 // transpose job
    int b = tid2 / 1176, rr = tid2 % 1176;
    int n0 = (rr % 98) * 32, c0 = (rr / 98) * 32;
    int r = t >> 3, q4 = (t & 7) * 4;
    size_t off = ((size_t)b * CIN + c0 + r) * NPIX + n0 + q4;
    if (f32) {
        float4 v = *(const float4*)((const float*)x + off);
        tile[r][q4 + 0] = f2bf(v.x);
        tile[r][q4 + 1] = f2bf(v.y);
        tile[r][q4 + 2] = f2bf(v.z);
        tile[r][q4 + 3] = f2bf(v.w);
    } else {
        vshort4 v = *(const vshort4*)((const short*)x + off);
#pragma unroll
        for (int i = 0; i < 4; i++) tile[r][q4 + i] = v[i];
    }
    __syncthreads();
    vshort4 o;
#pragma unroll
    for (int i = 0; i < 4; i++) o[i] = tile[q4 + i][r];
    *(vshort4*)(xT + ((size_t)b * NPIX + n0 + r) * CIN + c0 + q4) = o;
}

// ------- r3-proven GEMM body: C = A(·,K)·Bt(·,K)^T, 64x64 tile --------------
static __device__ __forceinline__ void gemm_body(
    short* Al, short* Bl,
    const short* __restrict__ A, const short* __restrict__ Bt,
    void* __restrict__ C, size_t coff, int m0, int n0,
    const float* __restrict__ sc, const float* __restrict__ sh,
    int Nb, int K, int bnPerRow, int finalOut, int f32)
{
    int t = threadIdx.x, lane = t & 63, w = t >> 6, m = lane & 15, quad = lane >> 4;
    int srow = t >> 2, scol = (t & 3) * 16;
    const short* ag = A + (size_t)(m0 + srow) * K + scol;
    const short* bg = Bt + (size_t)(n0 + srow) * K + scol;
    vfloat4 acc[4];
#pragma unroll
    for (int i = 0; i < 4; i++) acc[i] = (vfloat4){0.f, 0.f, 0.f, 0.f};

    for (int k0 = 0; k0 < K; k0 += 64) {
        vshort8 a0 = *(const vshort8*)(ag + k0);
        vshort8 a1 = *(const vshort8*)(ag + k0 + 8);
        vshort8 b0 = *(const vshort8*)(bg + k0);
        vshort8 b1 = *(const vshort8*)(bg + k0 + 8);
        __syncthreads();
        *(vshort8*)&Al[srow * 72 + scol] = a0;
        *(vshort8*)&Al[srow * 72 + scol + 8] = a1;
        *(vshort8*)&Bl[srow * 72 + scol] = b0;
        *(vshort8*)&Bl[srow * 72 + scol + 8] = b1;
        __syncthreads();
#pragma unroll
        for (int kk = 0; kk < 2; kk++) {
            vshort8 af = *(const vshort8*)&Al[(w * 16 + m) * 72 + kk * 32 + quad * 8];
#pragma unroll
            for (int nc = 0; nc < 4; nc++) {
                vshort8 bf = *(const vshort8*)&Bl[(nc * 16 + m) * 72 + kk * 32 + quad * 8];
                acc[nc] = __builtin_amdgcn_mfma_f32_16x16x32_bf16(af, bf, acc[nc], 0, 0, 0);
            }
        }
    }

#pragma unroll
    for (int nc = 0; nc < 4; nc++) {
        int col = n0 + nc * 16 + m;
        float scc = bnPerRow ? 0.f : sc[col];
        float shc = bnPerRow ? 0.f : sh[col];
#pragma unroll
        for (int r = 0; r < 4; r++) {
            int row = m0 + w * 16 + quad * 4 + r;
            float s2 = bnPerRow ? sc[row] : scc;
            float h2 = bnPerRow ? sh[row] : shc;
            float val = s2 * acc[nc][r] + h2;
            size_t idx = coff + (size_t)row * Nb + col;
            if (finalOut && f32) ((float*)C)[idx] = val;
            else                 ((short*)C)[idx] = f2bf(val);
        }
    }
}

// ======= proj: QK GEMM + V GEMM fused into one dispatch =====================
__global__ __launch_bounds__(256) void proj_kernel(
    const short* __restrict__ xT, const short* __restrict__ wqkB,
    const short* __restrict__ wvB, short* __restrict__ QKt,
    short* __restrict__ Vb,
    const float* __restrict__ scA, const float* __restrict__ shA)
{
    __shared__ __attribute__((aligned(16))) short Al[64 * 72];
    __shared__ __attribute__((aligned(16))) short Bl[64 * 72];
    int id = blockIdx.x;
    if (id < 392) {
        int b = id / 196, r = id % 196;
        int m0 = (r % 49) * 64, n0 = (r / 49) * 64;
        gemm_body(Al, Bl, xT + (size_t)b * NPIX * CIN, wqkB,
                  QKt, (size_t)b * NPIX * QKW, m0, n0,
                  scA, shA, QKW, CIN, 0, 0, 0);
    } else {
        id -= 392;
        int b = id / 392, r = id % 392;
        int m0 = (r % 8) * 64, n0 = (r / 8) * 64;
        gemm_body(Al, Bl, wvB, xT + (size_t)b * NPIX * CIN,
                  Vb, (size_t)b * DHD * NPIX, m0, n0,
                  scA + 256, shA + 256, NPIX, CIN, 1, 0, 0);
    }
}

// ======= final P GEMM: out (384,N) = wp·relu(xx)^T, dual-dtype store ========
__global__ __launch_bounds__(256) void pgemm_kernel(
    const short* __restrict__ wpB, const short* __restrict__ xx,
    void* __restrict__ out,
    const float* __restrict__ scA, const float* __restrict__ shA,
    const void* __restrict__ x)
{
    __shared__ __attribute__((aligned(16))) short Al[64 * 72];
    __shared__ __attribute__((aligned(16))) short Bl[64 * 72];
    int f32 = detect_f32((const unsigned short*)x);
    int id = blockIdx.x;
    int b = id / 294, r = id % 294;
    int m0 = (r % 6) * 64, n0 = (r / 6) * 64;
    gemm_body(Al, Bl, wpB, xx + (size_t)b * NPIX * DHD,
              out, (size_t)b * CIN * NPIX, m0, n0,
              scA + 768, shA + 768, NPIX, DHD, 1, 1, f32);
}

// ======= flash attention v4: barrier-free key-split waves ===================
// 4 waves/block, 64 queries/block. Waves {0,1}=even key tiles, {2,3}=odd:
// 2x wave parallelism (3136 waves), zero barriers in the main loop.
// P never touches LDS: swapped QK^T keeps the P-row lane-local; cvt_pk_bf16
// + permlane32_swap assemble the PV A-fragments in-register (T12).
// K/V read directly from global (L2-resident; same 16B/lane scatter the old
// LDS staging had). K tile t+1 register-prefetched. Denominator via ones-MFMA
// (bf16-rounded P, numerics identical to v3). One combine barrier at the end.
__global__ __launch_bounds__(256) void attn_kernel(
    const short* __restrict__ QKt, const short* __restrict__ V,
    short* __restrict__ xx)
{
    // transposed exchange: [writer-par][qgroup][o:16|L:16][lane] — conflict-free
    __shared__ float ex[2][2][32][64];

    int bh = blockIdx.y, b = bh >> 3, h = bh & 7;
    int q0 = blockIdx.x * 64;
    int t = threadIdx.x, lane = t & 63, w = t >> 6;
    int c31 = lane & 31, half = lane >> 5;
    int p = w & 1;        // query group: 0 -> q0..q0+31, 1 -> q0+32..q0+63
    int par = w >> 1;     // key-tile parity: 0 -> tiles 0,2,..,48  1 -> 1,3,..,47
    int nt = 25 - par;

    // Q fragment (B operand): lane holds Q[query=c31][kd=half*8+j]
    int q = q0 + p * 32 + c31;
    vshort8 aq = *(const vshort8*)(QKt + ((size_t)b * NPIX + q) * QKW + h * KD + half * 8);

    // K rows (A operand): key = k0 + kg*32 + c31, kd = half*8+j
    const short* kp = QKt + ((size_t)b * NPIX + c31) * QKW + NHKD + h * KD + half * 8;
    // V rows (B operand): d-channel = c31 (+32), key = k0 + kc*16 + half*8+j
    const short* vp0 = V + ((size_t)(b * DHD) + h * DHEAD + c31) * NPIX + half * 8;
    const short* vp1 = vp0 + (size_t)32 * NPIX;

    vfloat16 o0, o1, oL, z16;
#pragma unroll
    for (int i = 0; i < 16; i++) { o0[i] = 0.f; o1[i] = 0.f; oL[i] = 0.f; z16[i] = 0.f; }
    const short one_bf = (short)0x3F80;
    const vshort8 ones = {one_bf, one_bf, one_bf, one_bf, one_bf, one_bf, one_bf, one_bf};

    int k0 = par * 64;
    vshort8 kf0 = *(const vshort8*)(kp + (size_t)k0 * QKW);
    vshort8 kf1 = *(const vshort8*)(kp + (size_t)(k0 + 32) * QKW);

    for (int i = 0; i < nt; i++) {
        // V loads for current tile (consumed after the exp phase)
        vshort8 vf[8];
#pragma unroll
        for (int kc = 0; kc < 4; kc++) {
            vf[kc * 2]     = *(const vshort8*)(vp0 + k0 + kc * 16);
            vf[kc * 2 + 1] = *(const vshort8*)(vp1 + k0 + kc * 16);
        }
        // K register-prefetch for this wave's next tile
        vshort8 kn0 = kf0, kn1 = kf1;
        if (i + 1 < nt) {
            kn0 = *(const vshort8*)(kp + (size_t)(k0 + 128) * QKW);
            kn1 = *(const vshort8*)(kp + (size_t)(k0 + 160) * QKW);
        }

#pragma unroll
        for (int kg = 0; kg < 2; kg++) {
            // S^T = K·Q^T: col = c31 = query, row r -> key kg*32+(r&3)+8*(r>>2)+4*half
            vfloat16 s = __builtin_amdgcn_mfma_f32_32x32x16_bf16(kg ? kf1 : kf0, aq, z16, 0, 0, 0);
            unsigned int pk[8];
#pragma unroll
            for (int j = 0; j < 8; j++) {
                float plo = __expf(s[2 * j]);
                float phi = __expf(s[2 * j + 1]);
                pk[j] = cvtpk(plo, phi);   // bf16 pair, RNE
            }
            // PV A-frag assembly: frag[j<4] from half0's block, frag[j>=4] from half1's
#pragma unroll
            for (int kc2 = 0; kc2 < 2; kc2++) {
                int kc = kg * 2 + kc2, o = kc2 * 4;
                vint2 s0 = __builtin_amdgcn_permlane32_swap((int)pk[o + 0], (int)pk[o + 2], false, false);
                vint2 s1 = __builtin_amdgcn_permlane32_swap((int)pk[o + 1], (int)pk[o + 3], false, false);
                vuint4 fr;
                fr[0] = (unsigned int)s0[0]; fr[1] = (unsigned int)s1[0];
                fr[2] = (unsigned int)s0[1]; fr[3] = (unsigned int)s1[1];
                vshort8 ap = __builtin_bit_cast(vshort8, fr);
                o0 = __builtin_amdgcn_mfma_f32_32x32x16_bf16(ap, vf[kc * 2],     o0, 0, 0, 0);
                o1 = __builtin_amdgcn_mfma_f32_32x32x16_bf16(ap, vf[kc * 2 + 1], o1, 0, 0, 0);
                oL = __builtin_amdgcn_mfma_f32_32x32x16_bf16(ap, ones,           oL, 0, 0, 0);
            }
        }
        kf0 = kn0; kf1 = kn1;
        k0 += 128;
    }

    // ---- combine across tile-parity partners (single barrier) ----
    if (par == 1) {
#pragma unroll
        for (int r = 0; r < 16; r++) {
            ex[1][p][r][lane]      = o0[r];
            ex[1][p][16 + r][lane] = oL[r];
        }
    } else {
#pragma unroll
        for (int r = 0; r < 16; r++) {
            ex[0][p][r][lane]      = o1[r];
            ex[0][p][16 + r][lane] = oL[r];
        }
    }
    __syncthreads();

    // epilogue: reg r -> query (r&3)+8*(r>>2)+4*half; par 0 stores d 0..31, par 1 d 32..63
#pragma unroll
    for (int r = 0; r < 16; r++) {
        float ov, Lv;
        if (par == 0) { ov = o0[r] + ex[1][p][r][lane]; Lv = oL[r] + ex[1][p][16 + r][lane]; }
        else          { ov = o1[r] + ex[0][p][r][lane]; Lv = oL[r] + ex[0][p][16 + r][lane]; }
        int ql = (r & 3) + 8 * (r >> 2) + 4 * half;
        int qrow = q0 + p * 32 + ql;
        float inv = 1.0f / Lv;
        size_t base = ((size_t)b * NPIX + qrow) * DHD + h * DHEAD + (par ? 32 : 0) + c31;
        xx[base] = f2bf(fmaxf(ov * inv, 0.f));
    }
}

extern "C" void kernel_launch(void* const* d_in, const int* in_sizes, int n_in,
                              void* d_out, int out_size, void* d_ws, size_t ws_size,
                              hipStream_t stream) {
    const void* x  = d_in[0];
    const void* wq = d_in[1];
    const void* qg = d_in[2];  const void* qb = d_in[3];
    const void* qm = d_in[4];  const void* qv = d_in[5];
    const void* wk = d_in[6];
    const void* kg = d_in[7];  const void* kb = d_in[8];
    const void* km = d_in[9];  const void* kv = d_in[10];
    const void* wv = d_in[11];
    const void* vg = d_in[12]; const void* vb = d_in[13];
    const void* vm = d_in[14]; const void* vv = d_in[15];
    const void* wp = d_in[16];
    const void* pg = d_in[17]; const void* pb = d_in[18];
    const void* pm = d_in[19]; const void* pv = d_in[20];

    short* xT  = (short*)d_ws;                           // (B,N,384) bf16
    short* wB  = xT + (size_t)B_ * NPIX * CIN;           // wq|wk|wv|wp bf16
    short* wqkB = wB;                                    // 256 x 384
    short* wvB  = wB + 98304;                            // 512 x 384
    short* wpB  = wB + 294912;                           // 384 x 512
    short* QKt = wB + 491520;                            // (B,N,256)
    short* Vb  = QKt + (size_t)B_ * NPIX * QKW;          // (B,512,N)
    short* xx  = Vb + (size_t)B_ * DHD * NPIX;           // (B,N,512)
    float* scA = (float*)(xx + (size_t)B_ * NPIX * DHD); // 1152 fp32
    float* shA = scA + 1152;

    prep_kernel<<<4272, 256, 0, stream>>>(
        x, wq, wk, wv, wp, wB, xT,
        qg, qb, qm, qv, kg, kb, km, kv,
        vg, vb, vm, vv, pg, pb, pm, pv, scA, shA);

    proj_kernel<<<1176, 256, 0, stream>>>(xT, wqkB, wvB, QKt, Vb, scA, shA);

    attn_kernel<<<dim3(NPIX / 64, B_ * NH), 256, 0, stream>>>(QKt, Vb, xx);

    pgemm_kernel<<<588, 256, 0, stream>>>(wpB, xx, d_out, scA, shA, x);
}

// Round 6
// 204.045 us; speedup vs baseline: 1.2368x; 1.2368x over previous
//
#include <hip/hip_runtime.h>
#include <hip/hip_bf16.h>

#define B_   2
#define CIN  384
#define NPIX 3136
#define NH   8
#define KD   16
#define DHEAD 64
#define NHKD 128
#define QKW  256
#define DHD  512
#define EPSW 1e-5f

typedef __attribute__((ext_vector_type(8))) short vshort8;
typedef __attribute__((ext_vector_type(4))) short vshort4;
typedef __attribute__((ext_vector_type(4))) float vfloat4;
typedef __attribute__((ext_vector_type(16))) float vfloat16;

static __device__ __forceinline__ float bf2f(short s) {
    unsigned int u = ((unsigned int)(unsigned short)s) << 16;
    return __builtin_bit_cast(float, u);
}
static __device__ __forceinline__ short f2bf(float f) {
    unsigned int u = __builtin_bit_cast(unsigned int, f);
    unsigned int lsb = (u >> 16) & 1u;
    u += 0x7fffu + lsb;
    return (short)(u >> 16);
}
static __device__ __forceinline__ float pget(const void* p, int i, int f32) {
    return f32 ? ((const float*)p)[i] : bf2f(((const short*)p)[i]);
}

// ---- inline dtype detect: fp32 low-halves carry wild exponent fields -------
static __device__ __forceinline__ int detect_f32(const unsigned short* x) {
    int lane = threadIdx.x & 63;
    bool big = false;
#pragma unroll
    for (int j = 0; j < 8; j++) {
        int e = (x[(lane * 8 + j) * 2] >> 7) & 0xFF;
        big = big || (e >= 0xC0);
    }
    unsigned long long bal = __ballot(big);
    return __popcll(bal) >= 32;
}

// ======= prep: convert weights + BN tables + transpose x, one dispatch ======
__global__ __launch_bounds__(256) void prep_kernel(
    const void* __restrict__ x,
    const void* __restrict__ wq, const void* __restrict__ wk,
    const void* __restrict__ wv, const void* __restrict__ wp,
    short* __restrict__ wB, short* __restrict__ xT,
    const void* qg, const void* qb, const void* qm, const void* qv,
    const void* kg, const void* kb, const void* km, const void* kv,
    const void* vg, const void* vb, const void* vm, const void* vv,
    const void* pg, const void* pb, const void* pm, const void* pv,
    float* __restrict__ scA, float* __restrict__ shA)
{
    __shared__ short tile[32][33];
    int f32 = detect_f32((const unsigned short*)x);
    int id = blockIdx.x;
    int t = threadIdx.x;

    if (id < 1920) {
        int i = id * 256 + t;
        const void* src; int j;
        if (i < 49152)       { src = wq; j = i; }
        else if (i < 98304)  { src = wk; j = i - 49152; }
        else if (i < 294912) { src = wv; j = i - 98304; }
        else                 { src = wp; j = i - 294912; }
        wB[i] = f32 ? f2bf(((const float*)src)[j]) : ((const short*)src)[j];
        if (i < 1152) {
            const void *g, *bb, *mn, *vr;
            if (i < 128)      { g = qg; bb = qb; mn = qm; vr = qv; j = i; }
            else if (i < 256) { g = kg; bb = kb; mn = km; vr = kv; j = i - 128; }
            else if (i < 768) { g = vg; bb = vb; mn = vm; vr = vv; j = i - 256; }
            else              { g = pg; bb = pb; mn = pm; vr = pv; j = i - 768; }
            float iv = rsqrtf(pget(vr, j, f32) + EPSW);
            float s = pget(g, j, f32) * iv;
            scA[i] = s;
            shA[i] = pget(bb, j, f32) - pget(mn, j, f32) * s;
        }
        return;
    }

    int tid2 = id - 1920;                 // transpose job
    int b = tid2 / 1176, rr = tid2 % 1176;
    int n0 = (rr % 98) * 32, c0 = (rr / 98) * 32;
    int r = t >> 3, q4 = (t & 7) * 4;
    size_t off = ((size_t)b * CIN + c0 + r) * NPIX + n0 + q4;
    if (f32) {
        float4 v = *(const float4*)((const float*)x + off);
        tile[r][q4 + 0] = f2bf(v.x);
        tile[r][q4 + 1] = f2bf(v.y);
        tile[r][q4 + 2] = f2bf(v.z);
        tile[r][q4 + 3] = f2bf(v.w);
    } else {
        vshort4 v = *(const vshort4*)((const short*)x + off);
#pragma unroll
        for (int i = 0; i < 4; i++) tile[r][q4 + i] = v[i];
    }
    __syncthreads();
    vshort4 o;
#pragma unroll
    for (int i = 0; i < 4; i++) o[i] = tile[q4 + i][r];
    *(vshort4*)(xT + ((size_t)b * NPIX + n0 + r) * CIN + c0 + q4) = o;
}

// ------- r3-proven GEMM body: C = A(·,K)·Bt(·,K)^T, 64x64 tile --------------
static __device__ __forceinline__ void gemm_body(
    short* Al, short* Bl,
    const short* __restrict__ A, const short* __restrict__ Bt,
    void* __restrict__ C, size_t coff, int m0, int n0,
    const float* __restrict__ sc, const float* __restrict__ sh,
    int Nb, int K, int bnPerRow, int finalOut, int f32)
{
    int t = threadIdx.x, lane = t & 63, w = t >> 6, m = lane & 15, quad = lane >> 4;
    int srow = t >> 2, scol = (t & 3) * 16;
    const short* ag = A + (size_t)(m0 + srow) * K + scol;
    const short* bg = Bt + (size_t)(n0 + srow) * K + scol;
    vfloat4 acc[4];
#pragma unroll
    for (int i = 0; i < 4; i++) acc[i] = (vfloat4){0.f, 0.f, 0.f, 0.f};

    for (int k0 = 0; k0 < K; k0 += 64) {
        vshort8 a0 = *(const vshort8*)(ag + k0);
        vshort8 a1 = *(const vshort8*)(ag + k0 + 8);
        vshort8 b0 = *(const vshort8*)(bg + k0);
        vshort8 b1 = *(const vshort8*)(bg + k0 + 8);
        __syncthreads();
        *(vshort8*)&Al[srow * 72 + scol] = a0;
        *(vshort8*)&Al[srow * 72 + scol + 8] = a1;
        *(vshort8*)&Bl[srow * 72 + scol] = b0;
        *(vshort8*)&Bl[srow * 72 + scol + 8] = b1;
        __syncthreads();
#pragma unroll
        for (int kk = 0; kk < 2; kk++) {
            vshort8 af = *(const vshort8*)&Al[(w * 16 + m) * 72 + kk * 32 + quad * 8];
#pragma unroll
            for (int nc = 0; nc < 4; nc++) {
                vshort8 bf = *(const vshort8*)&Bl[(nc * 16 + m) * 72 + kk * 32 + quad * 8];
                acc[nc] = __builtin_amdgcn_mfma_f32_16x16x32_bf16(af, bf, acc[nc], 0, 0, 0);
            }
        }
    }

#pragma unroll
    for (int nc = 0; nc < 4; nc++) {
        int col = n0 + nc * 16 + m;
        float scc = bnPerRow ? 0.f : sc[col];
        float shc = bnPerRow ? 0.f : sh[col];
#pragma unroll
        for (int r = 0; r < 4; r++) {
            int row = m0 + w * 16 + quad * 4 + r;
            float s2 = bnPerRow ? sc[row] : scc;
            float h2 = bnPerRow ? sh[row] : shc;
            float val = s2 * acc[nc][r] + h2;
            size_t idx = coff + (size_t)row * Nb + col;
            if (finalOut && f32) ((float*)C)[idx] = val;
            else                 ((short*)C)[idx] = f2bf(val);
        }
    }
}

// ======= proj: QK GEMM + V GEMM fused into one dispatch =====================
__global__ __launch_bounds__(256) void proj_kernel(
    const short* __restrict__ xT, const short* __restrict__ wqkB,
    const short* __restrict__ wvB, short* __restrict__ QKt,
    short* __restrict__ Vb,
    const float* __restrict__ scA, const float* __restrict__ shA)
{
    __shared__ __attribute__((aligned(16))) short Al[64 * 72];
    __shared__ __attribute__((aligned(16))) short Bl[64 * 72];
    int id = blockIdx.x;
    if (id < 392) {
        int b = id / 196, r = id % 196;
        int m0 = (r % 49) * 64, n0 = (r / 49) * 64;
        gemm_body(Al, Bl, xT + (size_t)b * NPIX * CIN, wqkB,
                  QKt, (size_t)b * NPIX * QKW, m0, n0,
                  scA, shA, QKW, CIN, 0, 0, 0);
    } else {
        id -= 392;
        int b = id / 392, r = id % 392;
        int m0 = (r % 8) * 64, n0 = (r / 8) * 64;
        gemm_body(Al, Bl, wvB, xT + (size_t)b * NPIX * CIN,
                  Vb, (size_t)b * DHD * NPIX, m0, n0,
                  scA + 256, shA + 256, NPIX, CIN, 1, 0, 0);
    }
}

// ======= final P GEMM: out (384,N) = wp·relu(xx)^T, dual-dtype store ========
__global__ __launch_bounds__(256) void pgemm_kernel(
    const short* __restrict__ wpB, const short* __restrict__ xx,
    void* __restrict__ out,
    const float* __restrict__ scA, const float* __restrict__ shA,
    const void* __restrict__ x)
{
    __shared__ __attribute__((aligned(16))) short Al[64 * 72];
    __shared__ __attribute__((aligned(16))) short Bl[64 * 72];
    int f32 = detect_f32((const unsigned short*)x);
    int id = blockIdx.x;
    int b = id / 294, r = id % 294;
    int m0 = (r % 6) * 64, n0 = (r / 6) * 64;
    gemm_body(Al, Bl, wpB, xx + (size_t)b * NPIX * DHD,
              out, (size_t)b * CIN * NPIX, m0, n0,
              scA + 768, shA + 768, NPIX, DHD, 1, 1, f32);
}

// ======= flash attention v7: v3-proven body + block-level key split =========
// Body is the harness-proven v3 kernel verbatim (2 waves, dbuf Kl/Vl, Pl in
// LDS, ones-MFMA denominator).  blockIdx.z ∈ {0,1} splits the 49 key-tiles
// (z=0: tiles 0..24, z=1: 25..48) -> 1568 blocks, 2x wave parallelism.
// Epilogue stores raw f32 partials (O, L) to workspace; attn_combine divides.
__global__ __launch_bounds__(128) void attn_kernel(
    const short* __restrict__ QKt, const short* __restrict__ V,
    float* __restrict__ Op, float* __restrict__ Lp)
{
    __shared__ __attribute__((aligned(16))) short Kl[2][64 * 16];  // [key][kd]
    __shared__ __attribute__((aligned(16))) short Vl[2][64 * 72];  // [d][key]
    __shared__ __attribute__((aligned(16))) short Pl[64 * 72];     // [q][key]
    int bh = blockIdx.y, b = bh >> 3, h = bh & 7;
    int q0 = blockIdx.x * 64;
    int z = blockIdx.z;
    int t = threadIdx.x, lane = t & 63, w = t >> 6;
    int c31 = lane & 31, half = lane >> 5;

    // Q fragment (B operand): lane holds Q[query=c31][kd=half*8+j]
    int q = q0 + w * 32 + c31;
    vshort8 aq = *(const vshort8*)(QKt + ((size_t)b * NPIX + q) * QKW + h * KD + half * 8);

    vfloat16 o0, o1, oL, z16;
#pragma unroll
    for (int i = 0; i < 16; i++) { o0[i] = 0.f; o1[i] = 0.f; oL[i] = 0.f; z16[i] = 0.f; }

    // K staging: 128 threads, key = t>>1, kd-half = (t&1)*8 -> full 64x16 tile
    int kkey = t >> 1, kofs = (t & 1) * 8;
    const short* kgp = QKt + (size_t)b * NPIX * QKW + NHKD + h * KD + kofs;
    int vd = t >> 1, vkh = (t & 1) * 32;
    const short* vgp = V + ((size_t)(b * DHD) + h * DHEAD + vd) * NPIX + vkh;
    const short one_bf = (short)0x3F80;
    const vshort8 ones = {one_bf, one_bf, one_bf, one_bf, one_bf, one_bf, one_bf, one_bf};

    int kbase = z * 25 * 64;          // first key of this block's range
    int nt = z ? 24 : 25;             // tiles 25..48 / 0..24

    // prologue: stage first tile into buffer 0
    *(vshort8*)&Kl[0][kkey * 16 + kofs] = *(const vshort8*)(kgp + (size_t)(kbase + kkey) * QKW);
#pragma unroll
    for (int i = 0; i < 4; i++)
        *(vshort8*)&Vl[0][vd * 72 + vkh + i * 8] = *(const vshort8*)(vgp + kbase + i * 8);
    __syncthreads();

    for (int it = 0; it < nt; ++it) {
        int cur = it & 1, nxt = cur ^ 1;
        int k0 = kbase + it * 64;
        bool more = (it + 1) < nt;
        vshort8 ks, vs[4];
        if (more) {   // register prefetch of next tile
            ks = *(const vshort8*)(kgp + (size_t)(k0 + 64 + kkey) * QKW);
#pragma unroll
            for (int i = 0; i < 4; i++)
                vs[i] = *(const vshort8*)(vgp + k0 + 64 + i * 8);
        }

        // S^T = K·Q^T, two 32-key groups; exp + truncation-pack into Pl
        short* pw = &Pl[(w * 32 + c31) * 72];
#pragma unroll
        for (int kg = 0; kg < 2; kg++) {
            vshort8 ak = *(const vshort8*)&Kl[cur][(kg * 32 + c31) * 16 + half * 8];
            vfloat16 s = __builtin_amdgcn_mfma_f32_32x32x16_bf16(ak, aq, z16, 0, 0, 0);
#pragma unroll
            for (int rb = 0; rb < 4; rb++) {
                vshort4 pv;
#pragma unroll
                for (int j = 0; j < 4; j++) {
                    float p = __expf(s[rb * 4 + j]);
                    pv[j] = (short)(__builtin_bit_cast(unsigned int, p) >> 16);
                }
                // key = kg*32 + 4*half + 8*rb + j  (C-layout row formula)
                *(vshort4*)&pw[kg * 32 + half * 4 + rb * 8] = pv;
            }
        }
        // wave-private P rows: in-order DS pipe -> no barrier write->read

        // P·V (+ ones column -> denominator, reg-aligned with O)
#pragma unroll
        for (int kc = 0; kc < 4; kc++) {
            vshort8 ap  = *(const vshort8*)&Pl[(w * 32 + c31) * 72 + kc * 16 + half * 8];
            vshort8 bv0 = *(const vshort8*)&Vl[cur][(c31) * 72 + kc * 16 + half * 8];
            vshort8 bv1 = *(const vshort8*)&Vl[cur][(32 + c31) * 72 + kc * 16 + half * 8];
            o0 = __builtin_amdgcn_mfma_f32_32x32x16_bf16(ap, bv0, o0, 0, 0, 0);
            o1 = __builtin_amdgcn_mfma_f32_32x32x16_bf16(ap, bv1, o1, 0, 0, 0);
            oL = __builtin_amdgcn_mfma_f32_32x32x16_bf16(ap, ones, oL, 0, 0, 0);
        }

        if (more) {   // write prefetched tile into the other buffer
            *(vshort8*)&Kl[nxt][kkey * 16 + kofs] = ks;
#pragma unroll
            for (int i = 0; i < 4; i++)
                *(vshort8*)&Vl[nxt][vd * 72 + vkh + i * 8] = vs[i];
        }
        __syncthreads();   // single barrier per iter
    }

    // epilogue: reg r -> query (r&3)+8*(r>>2)+4*half; col c31 = d-channel.
    // Store raw partials; attn_combine sums the two z-halves and divides.
#pragma unroll
    for (int r = 0; r < 16; r++) {
        int ql = (r & 3) + 8 * (r >> 2) + 4 * half;
        int qrow = q0 + w * 32 + ql;
        size_t pb = (((size_t)z * 16 + bh) * NPIX + qrow) * 64 + c31;
        Op[pb]      = o0[r];
        Op[pb + 32] = o1[r];
        if (c31 == 0) Lp[((size_t)z * 16 + bh) * NPIX + qrow] = oL[r];
    }
}

// ======= combine: xx = relu((O0+O1)/(L0+L1)), bf16 ==========================
__global__ __launch_bounds__(256) void attn_combine(
    const float* __restrict__ Op, const float* __restrict__ Lp,
    short* __restrict__ xx)
{
    int idx = blockIdx.x * 256 + threadIdx.x;     // one float4 of d per thread
    int d4 = idx & 15;
    int rest = idx >> 4;
    int qq = rest % NPIX, bh = rest / NPIX;
    const size_t zO = (size_t)16 * NPIX * 64;
    const size_t zL = (size_t)16 * NPIX;
    size_t base = ((size_t)bh * NPIX + qq) * 64 + d4 * 4;
    float4 a = *(const float4*)(Op + base);
    float4 c = *(const float4*)(Op + base + zO);
    float L = Lp[(size_t)bh * NPIX + qq] + Lp[zL + (size_t)bh * NPIX + qq];
    float inv = 1.0f / L;
    int b = bh >> 3, h = bh & 7;
    vshort4 o;
    o[0] = f2bf(fmaxf((a.x + c.x) * inv, 0.f));
    o[1] = f2bf(fmaxf((a.y + c.y) * inv, 0.f));
    o[2] = f2bf(fmaxf((a.z + c.z) * inv, 0.f));
    o[3] = f2bf(fmaxf((a.w + c.w) * inv, 0.f));
    *(vshort4*)&xx[((size_t)b * NPIX + qq) * DHD + h * DHEAD + d4 * 4] = o;
}

extern "C" void kernel_launch(void* const* d_in, const int* in_sizes, int n_in,
                              void* d_out, int out_size, void* d_ws, size_t ws_size,
                              hipStream_t stream) {
    const void* x  = d_in[0];
    const void* wq = d_in[1];
    const void* qg = d_in[2];  const void* qb = d_in[3];
    const void* qm = d_in[4];  const void* qv = d_in[5];
    const void* wk = d_in[6];
    const void* kg = d_in[7];  const void* kb = d_in[8];
    const void* km = d_in[9];  const void* kv = d_in[10];
    const void* wv = d_in[11];
    const void* vg = d_in[12]; const void* vb = d_in[13];
    const void* vm = d_in[14]; const void* vv = d_in[15];
    const void* wp = d_in[16];
    const void* pg = d_in[17]; const void* pb = d_in[18];
    const void* pm = d_in[19]; const void* pv = d_in[20];

    short* xT  = (short*)d_ws;                           // (B,N,384) bf16
    short* wB  = xT + (size_t)B_ * NPIX * CIN;           // wq|wk|wv|wp bf16
    short* wqkB = wB;                                    // 256 x 384
    short* wvB  = wB + 98304;                            // 512 x 384
    short* wpB  = wB + 294912;                           // 384 x 512
    short* QKt = wB + 491520;                            // (B,N,256)
    short* Vb  = QKt + (size_t)B_ * NPIX * QKW;          // (B,512,N)
    short* xx  = Vb + (size_t)B_ * DHD * NPIX;           // (B,N,512)
    float* scA = (float*)(xx + (size_t)B_ * NPIX * DHD); // 1152 fp32
    float* shA = scA + 1152;
    float* Op  = shA + 1152;                             // [2][16][N][64] f32
    float* Lp  = Op + (size_t)2 * 16 * NPIX * 64;        // [2][16][N] f32

    prep_kernel<<<4272, 256, 0, stream>>>(
        x, wq, wk, wv, wp, wB, xT,
        qg, qb, qm, qv, kg, kb, km, kv,
        vg, vb, vm, vv, pg, pb, pm, pv, scA, shA);

    proj_kernel<<<1176, 256, 0, stream>>>(xT, wqkB, wvB, QKt, Vb, scA, shA);

    attn_kernel<<<dim3(NPIX / 64, B_ * NH, 2), 128, 0, stream>>>(QKt, Vb, Op, Lp);

    attn_combine<<<3136, 256, 0, stream>>>(Op, Lp, xx);

    pgemm_kernel<<<588, 256, 0, stream>>>(wpB, xx, d_out, scA, shA, x);
}